// Round 6
// baseline (60.231 us; speedup 1.0000x reference)
//
#include <hip/hip_runtime.h>
#include <math.h>

#define DD  64         // feature dim (fixed by problem)
#define CPB 128        // chunks (blocks) per batch -> 2048 streams, 8/CU
#define PSTRIDE 68     // floats per partial slot: 64 U + S + D (+pad)

__global__ void ha_init(float* ws, int count) {
    int i = blockIdx.x * blockDim.x + threadIdx.x;
    if (i < count) ws[i] = 0.0f;
}

__device__ __forceinline__ float dot4(float4 a, float4 b) {
    return a.x*b.x + a.y*b.y + a.z*b.z + a.w*b.w;
}

template <int CTRL>
__device__ __forceinline__ float dpp_add(float x) {
    int yi = __builtin_amdgcn_mov_dpp(__builtin_bit_cast(int, x), CTRL, 0xF, 0xF, true);
    return x + __builtin_bit_cast(float, yi);
}
// sum across each 8-lane group: quad xor1, quad xor2, row_half_mirror
__device__ __forceinline__ float r8(float x) {
    x = dpp_add<0xB1>(x);
    x = dpp_add<0x4E>(x);
    x = dpp_add<0x141>(x);
    return x;
}

__global__ __launch_bounds__(256, 8) void ha_main(
    const float* __restrict__ key, const float* __restrict__ query,
    const float* __restrict__ value, const float* __restrict__ betap,
    const float* __restrict__ cp,
    float* __restrict__ wsP,                       // partials (usePartials==1)
    float* __restrict__ wsU, float* __restrict__ wsS, float* __restrict__ wsD,
    int usePartials, int N)
{
    const int b     = blockIdx.x / CPB;
    const int chunk = blockIdx.x - b * CPB;
    const int npc   = (N + CPB - 1) / CPB;
    const int n0    = chunk * npc;
    const int nend  = min(n0 + npc, N);

    const int t    = threadIdx.x;
    const int wave = t >> 6;
    const int l    = t & 63;
    const int g    = l >> 3;   // row-group within wave (0..7)
    const int s    = l & 7;    // sub-lane: owns float4 cols s and s+8

    const float beta = betap[0];
    const float cc   = cp[0];
    // analytic softmax shift: dist <= 2*atanh(1-1e-5); e = exp2(beta*log2(ratio)+s2)
    const float dmax  = logf((2.0f - 1e-5f) / 1e-5f);
    const float mb    = fmaxf(beta * dmax, 0.0f) - cc;
    const float LOG2E = 1.4426950408889634f;
    const float s2    = -(cc + mb) * LOG2E;

    const float4* __restrict__ q4p = reinterpret_cast<const float4*>(query) + b * (DD / 4);
    const float4 qa = q4p[s], qb = q4p[s + 8];
    const float q2 = r8(dot4(qa, qa) + dot4(qb, qb));

    const float4* __restrict__ key4 =
        reinterpret_cast<const float4*>(key) + (size_t)b * N * (DD / 4);
    const float4* __restrict__ val4 =
        reinterpret_cast<const float4*>(value) + (size_t)b * N * (DD / 4);

    float4 accA = {0,0,0,0}, accB = {0,0,0,0};
    float aS = 0.f, aD = 0.f;

    #define HA_SET(K0, K1, V0, V1, OK)                                             \
    {                                                                              \
        float k2 = r8(dot4(K0, K0) + dot4(K1, K1));                                \
        float kq = r8(dot4(K0, qa) + dot4(K1, qb));                                \
        float v2 = r8(dot4(V0, V0) + dot4(V1, V1));                                \
        const float A    = 1.0f - 2.0f * kq + q2;                                  \
        const float C    = 1.0f - k2;                                              \
        const float den  = fmaxf(1.0f - 2.0f * kq + k2 * q2, 1e-15f);              \
        const float num2 = fmaxf(A*A*k2 + C*C*q2 - 2.0f*A*C*kq, 0.0f);             \
        float rr = __builtin_amdgcn_sqrtf(num2) * __builtin_amdgcn_rcpf(den);      \
        rr = fminf(rr, 1.0f - 1e-5f);                                              \
        const float ratio = (1.0f + rr) * __builtin_amdgcn_rcpf(1.0f - rr);        \
        float e = __builtin_amdgcn_exp2f(                                          \
                      fmaf(beta, __builtin_amdgcn_logf(ratio), s2));               \
        if (!(OK)) e = 0.0f;                                                       \
        const float lamb = 2.0f * __builtin_amdgcn_rcpf(fmaxf(1.0f - v2, 1e-10f)); \
        const float el   = e * lamb;                                               \
        accA.x += el * V0.x; accA.y += el * V0.y;                                  \
        accA.z += el * V0.z; accA.w += el * V0.w;                                  \
        accB.x += el * V1.x; accB.y += el * V1.y;                                  \
        accB.z += el * V1.z; accB.w += el * V1.w;                                  \
        aS += e;                                                                   \
        aD += e * (lamb - 1.0f);                                                   \
    }

    if (((nend - n0) & 127) == 0) {
        // fast path: no row guards (every 128-row macro-iter complete)
        for (int n = n0 + wave * 32 + g; n < nend; n += 128) {
            const size_t b0 = (size_t)n * (DD / 4) + s;
            const float4 kA0 = key4[b0],       kA1 = key4[b0 + 8];
            const float4 kB0 = key4[b0 + 128], kB1 = key4[b0 + 136];
            const float4 kC0 = key4[b0 + 256], kC1 = key4[b0 + 264];
            const float4 kD0 = key4[b0 + 384], kD1 = key4[b0 + 392];
            const float4 vA0 = val4[b0],       vA1 = val4[b0 + 8];
            const float4 vB0 = val4[b0 + 128], vB1 = val4[b0 + 136];
            const float4 vC0 = val4[b0 + 256], vC1 = val4[b0 + 264];
            const float4 vD0 = val4[b0 + 384], vD1 = val4[b0 + 392];
            HA_SET(kA0, kA1, vA0, vA1, true)
            HA_SET(kB0, kB1, vB0, vB1, true)
            HA_SET(kC0, kC1, vC0, vC1, true)
            HA_SET(kD0, kD1, vD0, vD1, true)
        }
    } else {
        for (int n = n0 + wave * 32 + g; n < nend; n += 128) {
            const int  n1 = n + 8,  n2i = n + 16, n3 = n + 24;
            const bool ok1 = n1 < nend, ok2 = n2i < nend, ok3 = n3 < nend;
            const size_t b0 = (size_t)n * (DD / 4) + s;
            const size_t b1 = ok1 ? (size_t)n1  * (DD / 4) + s : b0;
            const size_t b2 = ok2 ? (size_t)n2i * (DD / 4) + s : b0;
            const size_t b3 = ok3 ? (size_t)n3  * (DD / 4) + s : b0;
            const float4 kA0 = key4[b0], kA1 = key4[b0 + 8];
            const float4 kB0 = key4[b1], kB1 = key4[b1 + 8];
            const float4 kC0 = key4[b2], kC1 = key4[b2 + 8];
            const float4 kD0 = key4[b3], kD1 = key4[b3 + 8];
            const float4 vA0 = val4[b0], vA1 = val4[b0 + 8];
            const float4 vB0 = val4[b1], vB1 = val4[b1 + 8];
            const float4 vC0 = val4[b2], vC1 = val4[b2 + 8];
            const float4 vD0 = val4[b3], vD1 = val4[b3 + 8];
            HA_SET(kA0, kA1, vA0, vA1, true)
            HA_SET(kB0, kB1, vB0, vB1, ok1)
            HA_SET(kC0, kC1, vC0, vC1, ok2)
            HA_SET(kD0, kD1, vD0, vD1, ok3)
        }
    }
    #undef HA_SET

    // reduce U across the 8 row-groups (same s): xor masks 8,16,32
    #pragma unroll
    for (int mk = 8; mk < 64; mk <<= 1) {
        accA.x += __shfl_xor(accA.x, mk, 64); accA.y += __shfl_xor(accA.y, mk, 64);
        accA.z += __shfl_xor(accA.z, mk, 64); accA.w += __shfl_xor(accA.w, mk, 64);
        accB.x += __shfl_xor(accB.x, mk, 64); accB.y += __shfl_xor(accB.y, mk, 64);
        accB.z += __shfl_xor(accB.z, mk, 64); accB.w += __shfl_xor(accB.w, mk, 64);
    }
    // scalars: 8x redundant per row; full-wave sum then /8
    #pragma unroll
    for (int mk = 1; mk < 64; mk <<= 1) {
        aS += __shfl_xor(aS, mk, 64);
        aD += __shfl_xor(aD, mk, 64);
    }

    __shared__ float ldsU[4][8][8];   // [wave][s][comp: accA 0..3, accB 4..7]
    __shared__ float ldsS[4];
    __shared__ float ldsD[4];
    if (l < 8) {
        ldsU[wave][l][0] = accA.x; ldsU[wave][l][1] = accA.y;
        ldsU[wave][l][2] = accA.z; ldsU[wave][l][3] = accA.w;
        ldsU[wave][l][4] = accB.x; ldsU[wave][l][5] = accB.y;
        ldsU[wave][l][6] = accB.z; ldsU[wave][l][7] = accB.w;
    }
    if (l == 0) { ldsS[wave] = aS * 0.125f; ldsD[wave] = aD * 0.125f; }
    __syncthreads();

    if (usePartials) {
        float* dst = wsP + (size_t)blockIdx.x * PSTRIDE;
        if (t < DD) {
            const int ss = (t & 31) >> 2;
            const int j  = (t >> 5) * 4 + (t & 3);
            dst[t] = ldsU[0][ss][j] + ldsU[1][ss][j]
                   + ldsU[2][ss][j] + ldsU[3][ss][j];
        }
        if (t == 0) {
            dst[64] = ldsS[0] + ldsS[1] + ldsS[2] + ldsS[3];
            dst[65] = ldsD[0] + ldsD[1] + ldsD[2] + ldsD[3];
        }
    } else {
        if (t < DD) {
            const int ss = (t & 31) >> 2;
            const int j  = (t >> 5) * 4 + (t & 3);
            atomicAdd(&wsU[b * DD + t],
                      ldsU[0][ss][j] + ldsU[1][ss][j] + ldsU[2][ss][j] + ldsU[3][ss][j]);
        }
        if (t == 0) {
            atomicAdd(&wsS[b], ldsS[0] + ldsS[1] + ldsS[2] + ldsS[3]);
            atomicAdd(&wsD[b], ldsD[0] + ldsD[1] + ldsD[2] + ldsD[3]);
        }
    }
}

__device__ __forceinline__ void ha_tail(float U, float S, float D,
                                        float* __restrict__ out, int b, int d, int N)
{
    const float num = U / S;
    const float den = D / S;
    const float tm  = num / fmaxf(den, 1e-10f);
    float n2 = tm * tm;
    #pragma unroll
    for (int mk = 1; mk < 64; mk <<= 1) n2 += __shfl_xor(n2, mk, 64);
    const float nn = sqrtf(n2);
    const float nc = fminf(fmaxf(nn, 1e-15f), 1.0f - 1e-5f);
    const float th  = nc / (1.0f + sqrtf(fmaxf(1.0f - nc * nc, 0.0f)));
    const float mid = th * (tm / fmaxf(nn, 1e-15f));
    out[b * DD + d] = (float)N * mid;
}

// partial-reduction finalize: one block per batch, one wave
__global__ void ha_final_p(const float* __restrict__ wsP, float* __restrict__ out, int N)
{
    const int b = blockIdx.x;
    const int d = threadIdx.x;   // 64 lanes
    const float* base = wsP + (size_t)b * CPB * PSTRIDE;
    float u = 0.f;
    #pragma unroll 8
    for (int c = 0; c < CPB; ++c) u += base[c * PSTRIDE + d];
    // lane d carries S/D of chunks d and d+64 (CPB=128)
    float sc = base[d * PSTRIDE + 64] + base[(d + 64) * PSTRIDE + 64];
    float dc = base[d * PSTRIDE + 65] + base[(d + 64) * PSTRIDE + 65];
    #pragma unroll
    for (int mk = 1; mk < 64; mk <<= 1) {
        sc += __shfl_xor(sc, mk, 64);
        dc += __shfl_xor(dc, mk, 64);
    }
    ha_tail(u, sc, dc, out, b, d, N);
}

__global__ void ha_final_a(const float* __restrict__ wsU, const float* __restrict__ wsS,
                           const float* __restrict__ wsD, float* __restrict__ out, int N)
{
    const int b = blockIdx.x;
    const int d = threadIdx.x;
    ha_tail(wsU[b * DD + d], wsS[b], wsD[b], out, b, d, N);
}

extern "C" void kernel_launch(void* const* d_in, const int* in_sizes, int n_in,
                              void* d_out, int out_size, void* d_ws, size_t ws_size,
                              hipStream_t stream) {
    const float* key   = (const float*)d_in[0];
    const float* query = (const float*)d_in[1];
    const float* value = (const float*)d_in[2];
    const float* beta  = (const float*)d_in[3];
    const float* c     = (const float*)d_in[4];
    float* out = (float*)d_out;

    const int BD = in_sizes[1];        // B*D
    const int B  = BD / DD;
    const int N  = in_sizes[0] / BD;   // 32768

    const size_t needP = (size_t)B * CPB * PSTRIDE * sizeof(float);
    const int usePartials = (ws_size >= needP) ? 1 : 0;

    if (usePartials) {
        float* wsP = (float*)d_ws;
        ha_main<<<B * CPB, 256, 0, stream>>>(key, query, value, beta, c,
                                             wsP, nullptr, nullptr, nullptr, 1, N);
        ha_final_p<<<B, 64, 0, stream>>>(wsP, out, N);
    } else {
        float* wsU = (float*)d_ws;         // B*DD
        float* wsS = wsU + B * DD;         // B
        float* wsD = wsS + B;              // B
        const int wcount = B * DD + 2 * B;
        ha_init<<<(wcount + 255) / 256, 256, 0, stream>>>((float*)d_ws, wcount);
        ha_main<<<B * CPB, 256, 0, stream>>>(key, query, value, beta, c,
                                             nullptr, wsU, wsS, wsD, 0, N);
        ha_final_a<<<B, DD, 0, stream>>>(wsU, wsS, wsD, out, N);
    }
}

// Round 7
// 49.830 us; speedup vs baseline: 1.2087x; 1.2087x over previous
//
#include <hip/hip_runtime.h>
#include <math.h>

#define DD  64         // feature dim (fixed by problem)
#define CPB 64         // chunks (blocks) per batch -> 1024 blocks (best: R5)
#define PSTRIDE 68     // floats per partial slot: 64 U + S + D (+pad)

__global__ void ha_init(float* ws, int count) {
    int i = blockIdx.x * blockDim.x + threadIdx.x;
    if (i < count) ws[i] = 0.0f;
}

__device__ __forceinline__ float dot4(float4 a, float4 b) {
    return a.x*b.x + a.y*b.y + a.z*b.z + a.w*b.w;
}

template <int CTRL>
__device__ __forceinline__ float dpp_add(float x) {
    int yi = __builtin_amdgcn_mov_dpp(__builtin_bit_cast(int, x), CTRL, 0xF, 0xF, true);
    return x + __builtin_bit_cast(float, yi);
}
// sum across each 8-lane group: quad xor1, quad xor2, row_half_mirror
__device__ __forceinline__ float r8(float x) {
    x = dpp_add<0xB1>(x);
    x = dpp_add<0x4E>(x);
    x = dpp_add<0x141>(x);
    return x;
}

__global__ __launch_bounds__(256, 4) void ha_main(
    const float* __restrict__ key, const float* __restrict__ query,
    const float* __restrict__ value, const float* __restrict__ betap,
    const float* __restrict__ cp,
    float* __restrict__ wsP,                       // partials (usePartials==1)
    float* __restrict__ wsU, float* __restrict__ wsS, float* __restrict__ wsD,
    int usePartials, int N)
{
    const int b     = blockIdx.x / CPB;
    const int chunk = blockIdx.x - b * CPB;
    const int npc   = (N + CPB - 1) / CPB;
    const int n0    = chunk * npc;
    const int nend  = min(n0 + npc, N);

    const int t    = threadIdx.x;
    const int wave = t >> 6;
    const int l    = t & 63;
    const int g    = l >> 3;   // row-group within wave (0..7)
    const int s    = l & 7;    // sub-lane: owns float4 cols s and s+8

    const float beta = betap[0];
    const float cc   = cp[0];
    // analytic softmax shift: dist <= 2*atanh(1-1e-5); e = exp2(beta*log2(ratio)+s2)
    const float dmax  = logf((2.0f - 1e-5f) / 1e-5f);
    const float mb    = fmaxf(beta * dmax, 0.0f) - cc;
    const float LOG2E = 1.4426950408889634f;
    const float s2    = -(cc + mb) * LOG2E;

    const float4* __restrict__ q4p = reinterpret_cast<const float4*>(query) + b * (DD / 4);
    const float4 qa = q4p[s], qb = q4p[s + 8];
    const float q2 = r8(dot4(qa, qa) + dot4(qb, qb));

    const float4* __restrict__ key4 =
        reinterpret_cast<const float4*>(key) + (size_t)b * N * (DD / 4);
    const float4* __restrict__ val4 =
        reinterpret_cast<const float4*>(value) + (size_t)b * N * (DD / 4);

    float4 accA = {0,0,0,0}, accB = {0,0,0,0};
    float aS = 0.f, aD = 0.f;

    // e from k-side scalars only
    #define HA_E(K0, K1, EOUT)                                                     \
    {                                                                              \
        float k2 = r8(dot4(K0, K0) + dot4(K1, K1));                                \
        float kq = r8(dot4(K0, qa) + dot4(K1, qb));                                \
        const float A    = 1.0f - 2.0f * kq + q2;                                  \
        const float C    = 1.0f - k2;                                              \
        const float den  = fmaxf(1.0f - 2.0f * kq + k2 * q2, 1e-15f);              \
        const float num2 = fmaxf(A*A*k2 + C*C*q2 - 2.0f*A*C*kq, 0.0f);             \
        float rr = __builtin_amdgcn_sqrtf(num2) * __builtin_amdgcn_rcpf(den);      \
        rr = fminf(rr, 1.0f - 1e-5f);                                              \
        const float ratio = (1.0f + rr) * __builtin_amdgcn_rcpf(1.0f - rr);        \
        EOUT = __builtin_amdgcn_exp2f(fmaf(beta, __builtin_amdgcn_logf(ratio), s2)); \
    }
    // v-side accumulate given e
    #define HA_V(E, V0, V1)                                                        \
    {                                                                              \
        float v2 = r8(dot4(V0, V0) + dot4(V1, V1));                                \
        const float lamb = 2.0f * __builtin_amdgcn_rcpf(fmaxf(1.0f - v2, 1e-10f)); \
        const float el   = (E) * lamb;                                             \
        accA.x += el * V0.x; accA.y += el * V0.y;                                  \
        accA.z += el * V0.z; accA.w += el * V0.w;                                  \
        accB.x += el * V1.x; accB.y += el * V1.y;                                  \
        accB.z += el * V1.z; accB.w += el * V1.w;                                  \
        aS += (E);                                                                 \
        aD += (E) * (lamb - 1.0f);                                                 \
    }

    if (((nend - n0) & 255) == 0) {
        // fast path: wave covers 64 rows/iter (8 sets of 8); block covers 256
        for (int n = n0 + wave * 64 + g; n < nend; n += 256) {
            const size_t b0 = (size_t)n * (DD / 4) + s;
            // phase K: 16 sequential-array loads in flight
            float4 k0[8], k1[8];
            #pragma unroll
            for (int j = 0; j < 8; ++j) {
                k0[j] = key4[b0 + (size_t)j * 128];
                k1[j] = key4[b0 + (size_t)j * 128 + 8];
            }
            float e[8];
            #pragma unroll
            for (int j = 0; j < 8; ++j) HA_E(k0[j], k1[j], e[j])
            // phase V: 16 sequential-array loads in flight
            float4 v0[8], v1[8];
            #pragma unroll
            for (int j = 0; j < 8; ++j) {
                v0[j] = val4[b0 + (size_t)j * 128];
                v1[j] = val4[b0 + (size_t)j * 128 + 8];
            }
            #pragma unroll
            for (int j = 0; j < 8; ++j) HA_V(e[j], v0[j], v1[j])
        }
    } else {
        // guarded path: 32 rows/iter (4 sets), per-set ok flags
        for (int n = n0 + wave * 32 + g; n < nend; n += 128) {
            const int  n1 = n + 8,  n2i = n + 16, n3 = n + 24;
            const bool ok1 = n1 < nend, ok2 = n2i < nend, ok3 = n3 < nend;
            const size_t b0 = (size_t)n * (DD / 4) + s;
            const size_t b1 = ok1 ? (size_t)n1  * (DD / 4) + s : b0;
            const size_t b2 = ok2 ? (size_t)n2i * (DD / 4) + s : b0;
            const size_t b3 = ok3 ? (size_t)n3  * (DD / 4) + s : b0;
            const float4 kA0 = key4[b0], kA1 = key4[b0 + 8];
            const float4 kB0 = key4[b1], kB1 = key4[b1 + 8];
            const float4 kC0 = key4[b2], kC1 = key4[b2 + 8];
            const float4 kD0 = key4[b3], kD1 = key4[b3 + 8];
            const float4 vA0 = val4[b0], vA1 = val4[b0 + 8];
            const float4 vB0 = val4[b1], vB1 = val4[b1 + 8];
            const float4 vC0 = val4[b2], vC1 = val4[b2 + 8];
            const float4 vD0 = val4[b3], vD1 = val4[b3 + 8];
            float eA, eB, eC, eD;
            HA_E(kA0, kA1, eA) HA_E(kB0, kB1, eB)
            HA_E(kC0, kC1, eC) HA_E(kD0, kD1, eD)
            if (!ok1) eB = 0.0f;
            if (!ok2) eC = 0.0f;
            if (!ok3) eD = 0.0f;
            HA_V(eA, vA0, vA1) HA_V(eB, vB0, vB1)
            HA_V(eC, vC0, vC1) HA_V(eD, vD0, vD1)
        }
    }
    #undef HA_E
    #undef HA_V

    // reduce U across the 8 row-groups (same s): xor masks 8,16,32
    #pragma unroll
    for (int mk = 8; mk < 64; mk <<= 1) {
        accA.x += __shfl_xor(accA.x, mk, 64); accA.y += __shfl_xor(accA.y, mk, 64);
        accA.z += __shfl_xor(accA.z, mk, 64); accA.w += __shfl_xor(accA.w, mk, 64);
        accB.x += __shfl_xor(accB.x, mk, 64); accB.y += __shfl_xor(accB.y, mk, 64);
        accB.z += __shfl_xor(accB.z, mk, 64); accB.w += __shfl_xor(accB.w, mk, 64);
    }
    // scalars: 8x redundant per row; full-wave sum then /8
    #pragma unroll
    for (int mk = 1; mk < 64; mk <<= 1) {
        aS += __shfl_xor(aS, mk, 64);
        aD += __shfl_xor(aD, mk, 64);
    }

    __shared__ float ldsU[4][8][8];   // [wave][s][comp: accA 0..3, accB 4..7]
    __shared__ float ldsS[4];
    __shared__ float ldsD[4];
    if (l < 8) {
        ldsU[wave][l][0] = accA.x; ldsU[wave][l][1] = accA.y;
        ldsU[wave][l][2] = accA.z; ldsU[wave][l][3] = accA.w;
        ldsU[wave][l][4] = accB.x; ldsU[wave][l][5] = accB.y;
        ldsU[wave][l][6] = accB.z; ldsU[wave][l][7] = accB.w;
    }
    if (l == 0) { ldsS[wave] = aS * 0.125f; ldsD[wave] = aD * 0.125f; }
    __syncthreads();

    if (usePartials) {
        float* dst = wsP + (size_t)blockIdx.x * PSTRIDE;
        if (t < DD) {
            const int ss = (t & 31) >> 2;
            const int j  = (t >> 5) * 4 + (t & 3);
            dst[t] = ldsU[0][ss][j] + ldsU[1][ss][j]
                   + ldsU[2][ss][j] + ldsU[3][ss][j];
        }
        if (t == 0) {
            dst[64] = ldsS[0] + ldsS[1] + ldsS[2] + ldsS[3];
            dst[65] = ldsD[0] + ldsD[1] + ldsD[2] + ldsD[3];
        }
    } else {
        if (t < DD) {
            const int ss = (t & 31) >> 2;
            const int j  = (t >> 5) * 4 + (t & 3);
            atomicAdd(&wsU[b * DD + t],
                      ldsU[0][ss][j] + ldsU[1][ss][j] + ldsU[2][ss][j] + ldsU[3][ss][j]);
        }
        if (t == 0) {
            atomicAdd(&wsS[b], ldsS[0] + ldsS[1] + ldsS[2] + ldsS[3]);
            atomicAdd(&wsD[b], ldsD[0] + ldsD[1] + ldsD[2] + ldsD[3]);
        }
    }
}

__device__ __forceinline__ void ha_tail(float U, float S, float D,
                                        float* __restrict__ out, int b, int d, int N)
{
    const float num = U / S;
    const float den = D / S;
    const float tm  = num / fmaxf(den, 1e-10f);
    float n2 = tm * tm;
    #pragma unroll
    for (int mk = 1; mk < 64; mk <<= 1) n2 += __shfl_xor(n2, mk, 64);
    const float nn = sqrtf(n2);
    const float nc = fminf(fmaxf(nn, 1e-15f), 1.0f - 1e-5f);
    const float th  = nc / (1.0f + sqrtf(fmaxf(1.0f - nc * nc, 0.0f)));
    const float mid = th * (tm / fmaxf(nn, 1e-15f));
    out[b * DD + d] = (float)N * mid;
}

// partial-reduction finalize: one block per batch, one wave
__global__ void ha_final_p(const float* __restrict__ wsP, float* __restrict__ out, int N)
{
    const int b = blockIdx.x;
    const int d = threadIdx.x;   // 64 lanes = CPB
    const float* base = wsP + (size_t)b * CPB * PSTRIDE;
    float u = 0.f;
    #pragma unroll 8
    for (int c = 0; c < CPB; ++c) u += base[c * PSTRIDE + d];
    float sc = base[d * PSTRIDE + 64];   // lane d carries chunk d's S
    float dc = base[d * PSTRIDE + 65];
    #pragma unroll
    for (int mk = 1; mk < 64; mk <<= 1) {
        sc += __shfl_xor(sc, mk, 64);
        dc += __shfl_xor(dc, mk, 64);
    }
    ha_tail(u, sc, dc, out, b, d, N);
}

__global__ void ha_final_a(const float* __restrict__ wsU, const float* __restrict__ wsS,
                           const float* __restrict__ wsD, float* __restrict__ out, int N)
{
    const int b = blockIdx.x;
    const int d = threadIdx.x;
    ha_tail(wsU[b * DD + d], wsS[b], wsD[b], out, b, d, N);
}

extern "C" void kernel_launch(void* const* d_in, const int* in_sizes, int n_in,
                              void* d_out, int out_size, void* d_ws, size_t ws_size,
                              hipStream_t stream) {
    const float* key   = (const float*)d_in[0];
    const float* query = (const float*)d_in[1];
    const float* value = (const float*)d_in[2];
    const float* beta  = (const float*)d_in[3];
    const float* c     = (const float*)d_in[4];
    float* out = (float*)d_out;

    const int BD = in_sizes[1];        // B*D
    const int B  = BD / DD;
    const int N  = in_sizes[0] / BD;   // 32768

    const size_t needP = (size_t)B * CPB * PSTRIDE * sizeof(float);
    const int usePartials = (ws_size >= needP) ? 1 : 0;

    if (usePartials) {
        float* wsP = (float*)d_ws;
        ha_main<<<B * CPB, 256, 0, stream>>>(key, query, value, beta, c,
                                             wsP, nullptr, nullptr, nullptr, 1, N);
        ha_final_p<<<B, 64, 0, stream>>>(wsP, out, N);
    } else {
        float* wsU = (float*)d_ws;         // B*DD
        float* wsS = wsU + B * DD;         // B
        float* wsD = wsS + B;              // B
        const int wcount = B * DD + 2 * B;
        ha_init<<<(wcount + 255) / 256, 256, 0, stream>>>((float*)d_ws, wcount);
        ha_main<<<B * CPB, 256, 0, stream>>>(key, query, value, beta, c,
                                             nullptr, wsU, wsS, wsD, 0, N);
        ha_final_a<<<B, DD, 0, stream>>>(wsU, wsS, wsD, out, N);
    }
}